// Round 2
// baseline (6842.809 us; speedup 1.0000x reference)
//
#include <hip/hip_runtime.h>
#include <hip/hip_bf16.h>
#include <math.h>

// Problem constants (B=2, S=2048, D=2048, H=16, HD=128, F=8192)
#define BB 2
#define SS 2048
#define DD 2048
#define HH 16
#define HD 128
#define FF 8192
#define MM (BB*SS)          // 4096 rows
#define CL 64               // scan chunk length
#define NC (SS/CL)          // 32 chunks
#define FCH 2048            // MLP F-chunk width (4 chunks)

#define DEVI __device__ __forceinline__

DEVI float gelu_f(float x) {
  float x3 = x * x * x;
  return 0.5f * x * (1.0f + tanhf(0.7978845608028654f * (x + 0.044715f * x3)));
}
DEVI float sigmoid_f(float x) { return 1.0f / (1.0f + expf(-x)); }

// ---------------- RMSNorm: one block per row of 2048 ----------------
__global__ __launch_bounds__(256) void rmsnorm_k(const float* __restrict__ x,
                                                 const float* __restrict__ w,
                                                 float* __restrict__ o) {
  size_t row = blockIdx.x;
  const float* xr = x + row * DD;
  float* orow = o + row * DD;
  int tid = threadIdx.x;
  float ss = 0.f;
#pragma unroll
  for (int i = 0; i < 2; ++i) {
    float4 v = *(const float4*)&xr[tid * 4 + i * 1024];
    ss += v.x * v.x + v.y * v.y + v.z * v.z + v.w * v.w;
  }
#pragma unroll
  for (int off = 32; off > 0; off >>= 1) ss += __shfl_down(ss, off, 64);
  __shared__ float sred[4];
  if ((tid & 63) == 0) sred[tid >> 6] = ss;
  __syncthreads();
  float scale = rsqrtf((sred[0] + sred[1] + sred[2] + sred[3]) * (1.0f / DD) + 1e-6f);
#pragma unroll
  for (int i = 0; i < 2; ++i) {
    int idx = tid * 4 + i * 1024;
    float4 v = *(const float4*)&xr[idx];
    float4 wv = *(const float4*)&w[idx];
    float4 r;
    r.x = v.x * scale * wv.x; r.y = v.y * scale * wv.y;
    r.z = v.z * scale * wv.z; r.w = v.w * scale * wv.w;
    *(float4*)&orow[idx] = r;
  }
}

// ---------------- causal depthwise conv1d, K=4 ----------------
__global__ __launch_bounds__(256) void conv_k(const float* __restrict__ xb,
                                              const float* __restrict__ cw,
                                              const float* __restrict__ cb,
                                              float* __restrict__ xc) {
  int idx = blockIdx.x * 256 + threadIdx.x;   // float4 index
  const int D4 = DD / 4;
  if (idx >= BB * SS * D4) return;
  int d4 = idx % D4;
  int bs = idx / D4;
  int s = bs % SS;
  int d = d4 * 4;
  float4 acc = *(const float4*)&cb[d];
  const float* base = xb + (size_t)(bs - s) * DD + d;  // start of batch b
#pragma unroll
  for (int k = 0; k < 4; ++k) {
    int sp = s + k - 3;
    if (sp >= 0) {
      float4 w = *(const float4*)&cw[k * DD + d];
      float4 v = *(const float4*)&base[(size_t)sp * DD];
      acc.x = fmaf(w.x, v.x, acc.x); acc.y = fmaf(w.y, v.y, acc.y);
      acc.z = fmaf(w.z, v.z, acc.z); acc.w = fmaf(w.w, v.w, acc.w);
    }
  }
  *(float4*)&xc[(size_t)bs * DD + d] = acc;
}

// ---------------- chunked scan: pass1 per-chunk aggregates ----------------
__global__ __launch_bounds__(256) void scan1_k(const float* __restrict__ a,
                                               const float* __restrict__ bx,
                                               float* __restrict__ cA,
                                               float* __restrict__ cB) {
  int idx = blockIdx.x * 256 + threadIdx.x;   // (b, c, d)
  if (idx >= BB * NC * DD) return;
  int d = idx % DD;
  int t = idx / DD;
  int c = t % NC;
  int b = t / NC;
  size_t base = ((size_t)b * SS + (size_t)c * CL) * DD + d;
  float A = 1.f, Bv = 0.f;
  for (int s = 0; s < CL; ++s) {
    float av = a[base + (size_t)s * DD];
    float bv = bx[base + (size_t)s * DD];
    A = av * A;
    Bv = fmaf(av, Bv, bv);
  }
  size_t o = ((size_t)b * NC + c) * DD + d;
  cA[o] = A;
  cB[o] = Bv;
}

// ---------------- scan pass2: across chunks, emit carries + h_last ----------------
__global__ __launch_bounds__(256) void scan2_k(const float* __restrict__ cA,
                                               const float* __restrict__ cB,
                                               const float* __restrict__ h0,
                                               float* __restrict__ carry,
                                               float* __restrict__ hlast) {
  int idx = blockIdx.x * 256 + threadIdx.x;   // (b, d)
  if (idx >= BB * DD) return;
  int d = idx % DD;
  int b = idx / DD;
  float h = h0[(size_t)b * DD + d];
  for (int c = 0; c < NC; ++c) {
    size_t o = ((size_t)b * NC + c) * DD + d;
    carry[o] = h;
    h = fmaf(cA[o], h, cB[o]);
  }
  hlast[(size_t)b * DD + d] = h;
}

// ---------------- scan pass3: within-chunk scan with carry ----------------
__global__ __launch_bounds__(256) void scan3_k(const float* __restrict__ a,
                                               const float* __restrict__ bx,
                                               const float* __restrict__ carry,
                                               float* __restrict__ lru) {
  int idx = blockIdx.x * 256 + threadIdx.x;
  if (idx >= BB * NC * DD) return;
  int d = idx % DD;
  int t = idx / DD;
  int c = t % NC;
  int b = t / NC;
  size_t base = ((size_t)b * SS + (size_t)c * CL) * DD + d;
  float h = carry[((size_t)b * NC + c) * DD + d];
  for (int s = 0; s < CL; ++s) {
    float av = a[base + (size_t)s * DD];
    float bv = bx[base + (size_t)s * DD];
    h = fmaf(av, h, bv);
    lru[base + (size_t)s * DD] = h;
  }
}

// ---------------- elementwise y *= lru ----------------
__global__ __launch_bounds__(256) void mul_k(float* __restrict__ y,
                                             const float* __restrict__ lru) {
  int i = blockIdx.x * 256 + threadIdx.x;
  if (i >= (MM * DD) / 4) return;
  float4 a = ((const float4*)y)[i];
  float4 b = ((const float4*)lru)[i];
  float4 r;
  r.x = a.x * b.x; r.y = a.y * b.y; r.z = a.z * b.z; r.w = a.w * b.w;
  ((float4*)y)[i] = r;
}

// ---------------- tiled GEMM, 64x64 tile, 4x4/thread, optional dual-B ----------------
// EPI_YX   : O0 = gelu(A@B0), O1 = A@B1
// EPI_GU   : O0 = gelu(A@B0) * (A@B1)
// EPI_GATES: per-head (z) RG-LRU gate math -> O0 = a, O1 = bx
// EPI_ADD  : O0 = A@B0 + aux0
enum { EPI_YX = 0, EPI_GU = 1, EPI_GATES = 2, EPI_ADD = 3 };

template <int EPI>
__global__ __launch_bounds__(256) void gemm_k(
    const float* __restrict__ A, const float* __restrict__ B0,
    const float* __restrict__ B1, float* __restrict__ O0,
    float* __restrict__ O1, const float* __restrict__ aux0,
    const float* __restrict__ aux1, const float* __restrict__ aux2,
    int M, int N, int K, int lda, int ldb, int ldc) {
  constexpr bool DUAL = (EPI != EPI_ADD);
  constexpr int BK = 16;
  __shared__ float As[BK][64 + 4];            // padded transpose store
  __shared__ float Bs0[BK][64];
  __shared__ float Bs1[DUAL ? BK : 1][DUAL ? 64 : 1];

  if constexpr (EPI == EPI_GATES) {
    int h = blockIdx.z;
    A += h * HD;
    B0 += h * HD * HD;
    B1 += h * HD * HD;
    O0 += h * HD;
    O1 += h * HD;
    aux0 += h * HD; aux1 += h * HD; aux2 += h * HD;
  }

  int tid = threadIdx.x;
  int tx = tid & 15, ty = tid >> 4;
  int m0 = blockIdx.y * 64, n0 = blockIdx.x * 64;
  int ar = tid >> 2, ac = (tid & 3) << 2;     // A tile: 64 rows x 16 cols
  int br = tid >> 4, bc = (tid & 15) << 2;    // B tile: 16 rows x 64 cols

  const float* Aptr = A + (size_t)(m0 + ar) * lda + ac;
  const float* B0ptr = B0 + (size_t)br * ldb + n0 + bc;
  const float* B1ptr = DUAL ? (B1 + (size_t)br * ldb + n0 + bc) : nullptr;

  float acc0[4][4] = {};
  float acc1[4][4] = {};

  for (int kk = 0; kk < K; kk += BK) {
    float4 av = *(const float4*)(Aptr + kk);
    float4 b0 = *(const float4*)(B0ptr + (size_t)kk * ldb);
    float4 b1 = {};
    if constexpr (DUAL) b1 = *(const float4*)(B1ptr + (size_t)kk * ldb);
    As[ac + 0][ar] = av.x; As[ac + 1][ar] = av.y;
    As[ac + 2][ar] = av.z; As[ac + 3][ar] = av.w;
    *(float4*)&Bs0[br][bc] = b0;
    if constexpr (DUAL) *(float4*)&Bs1[br][bc] = b1;
    __syncthreads();
#pragma unroll
    for (int k = 0; k < BK; ++k) {
      float4 a4 = *(const float4*)&As[k][ty << 2];
      float4 p4 = *(const float4*)&Bs0[k][tx << 2];
      float avr[4] = {a4.x, a4.y, a4.z, a4.w};
      float b0v[4] = {p4.x, p4.y, p4.z, p4.w};
      float b1v[4];
      if constexpr (DUAL) {
        float4 q4 = *(const float4*)&Bs1[k][tx << 2];
        b1v[0] = q4.x; b1v[1] = q4.y; b1v[2] = q4.z; b1v[3] = q4.w;
      }
#pragma unroll
      for (int i = 0; i < 4; ++i)
#pragma unroll
        for (int j = 0; j < 4; ++j) {
          acc0[i][j] = fmaf(avr[i], b0v[j], acc0[i][j]);
          if constexpr (DUAL) acc1[i][j] = fmaf(avr[i], b1v[j], acc1[i][j]);
        }
    }
    __syncthreads();
  }

  int grow = m0 + (ty << 2);
  int gcol = n0 + (tx << 2);
#pragma unroll
  for (int i = 0; i < 4; ++i) {
    size_t ro = (size_t)(grow + i) * ldc + gcol;
#pragma unroll
    for (int j = 0; j < 4; ++j) {
      if constexpr (EPI == EPI_YX) {
        O0[ro + j] = gelu_f(acc0[i][j]);
        O1[ro + j] = acc1[i][j];
      } else if constexpr (EPI == EPI_GU) {
        O0[ro + j] = gelu_f(acc0[i][j]) * acc1[i][j];
      } else if constexpr (EPI == EPI_ADD) {
        O0[ro + j] = acc0[i][j] + aux0[ro + j];
      } else {  // EPI_GATES
        float rv = sigmoid_f(acc0[i][j] + aux0[gcol + j]);   // agate
        float iv = sigmoid_f(acc1[i][j] + aux1[gcol + j]);   // igate
        float ap = aux2[gcol + j];                           // a_param
        float sp = log1pf(expf(-ap));                        // softplus(-a_param)
        float la = -8.0f * rv * sp;                          // log a
        float mult = sqrtf(fmaxf(1.0f - expf(2.0f * la), 0.0f));
        float xrv = A[(size_t)(grow + i) * lda + gcol + j];  // xr value
        O0[ro + j] = expf(la);                               // a
        O1[ro + j] = mult * iv * xrv;                        // bx
      }
    }
  }
}

extern "C" void kernel_launch(void* const* d_in, const int* in_sizes, int n_in,
                              void* d_out, int out_size, void* d_ws, size_t ws_size,
                              hipStream_t stream) {
  const float* x       = (const float*)d_in[0];
  const float* hidden  = (const float*)d_in[1];
  const float* rms1_w  = (const float*)d_in[2];
  const float* rms2_w  = (const float*)d_in[3];
  const float* W_x     = (const float*)d_in[4];
  const float* W_y     = (const float*)d_in[5];
  const float* conv_w  = (const float*)d_in[6];
  const float* conv_b  = (const float*)d_in[7];
  const float* a_param = (const float*)d_in[8];
  const float* igate_w = (const float*)d_in[9];
  const float* igate_b = (const float*)d_in[10];
  const float* agate_w = (const float*)d_in[11];
  const float* agate_b = (const float*)d_in[12];
  const float* W_out   = (const float*)d_in[13];
  const float* W_gate  = (const float*)d_in[14];
  const float* W_up    = (const float*)d_in[15];
  const float* W_down  = (const float*)d_in[16];

  float* out   = (float*)d_out;                 // [4096, 2048]
  float* hlast = out + (size_t)MM * DD;         // [2, 2048]

  // 4-slot rotating workspace: 4*E floats + 3 small scan buffers.
  // Total = (4*8388608 + 3*131072) * 4 B ~= 136 MB.
  const size_t E = (size_t)MM * DD;             // 8388608
  float* ws = (float*)d_ws;
  float* s0 = ws;                 // normed -> xc -> lru -> t(chunk)
  float* s1 = ws + E;             // y -> y*lru
  float* s2 = ws + 2 * E;         // xb -> a -> residual
  float* s3 = ws + 3 * E;         // bx -> n2
  float* cA    = ws + 4 * E;      // [B, NC, D]
  float* cB    = cA + (size_t)BB * NC * DD;
  float* carry = cB + (size_t)BB * NC * DD;

  // 1. normed = rmsnorm(x, rms1_w)                         -> s0
  rmsnorm_k<<<MM, 256, 0, stream>>>(x, rms1_w, s0);

  // 2. y = gelu(normed@W_y) -> s1 ; xb = normed@W_x -> s2
  gemm_k<EPI_YX><<<dim3(DD / 64, MM / 64), 256, 0, stream>>>(
      s0, W_y, W_x, s1, s2, nullptr, nullptr, nullptr,
      MM, DD, DD, DD, DD, DD);

  // 3. xc = causal depthwise conv(xb)                      -> s0 (normed dead)
  conv_k<<<(BB * SS * (DD / 4) + 255) / 256, 256, 0, stream>>>(s2, conv_w, conv_b, s0);

  // 4. gates from xc: a -> s2 (xb dead), bx -> s3
  gemm_k<EPI_GATES><<<dim3(HD / 64, MM / 64, HH), 256, 0, stream>>>(
      s0, agate_w, igate_w, s2, s3, agate_b, igate_b, a_param,
      MM, HD, HD, DD, HD, DD);

  // 5-7. chunked linear scan -> lru in s0 (xc dead), h_last -> d_out tail
  scan1_k<<<(BB * NC * DD + 255) / 256, 256, 0, stream>>>(s2, s3, cA, cB);
  scan2_k<<<(BB * DD + 255) / 256, 256, 0, stream>>>(cA, cB, hidden, carry, hlast);
  scan3_k<<<(BB * NC * DD + 255) / 256, 256, 0, stream>>>(s2, s3, carry, s0);

  // 8. y *= lru   (s1 *= s0)
  mul_k<<<(MM * DD / 4 + 255) / 256, 256, 0, stream>>>(s1, s0);

  // 9. residual = (y*lru)@W_out + x                        -> s2 (a dead)
  gemm_k<EPI_ADD><<<dim3(DD / 64, MM / 64), 256, 0, stream>>>(
      s1, W_out, nullptr, s2, nullptr, x, nullptr, nullptr,
      MM, DD, DD, DD, DD, DD);

  // 10. n2 = rmsnorm(residual, rms2_w)                     -> s3 (bx dead)
  rmsnorm_k<<<MM, 256, 0, stream>>>(s2, rms2_w, s3);

  // 11+12. gated MLP chunked over F (4 chunks of 2048):
  //   t_c = gelu(n2@W_gate[:,c]) * (n2@W_up[:,c])          -> s0 (lru dead)
  //   out = t_c @ W_down[c,:] + (c==0 ? residual : out)
  for (int c = 0; c < FF / FCH; ++c) {
    const float* Wg = W_gate + (size_t)c * FCH;
    const float* Wu = W_up   + (size_t)c * FCH;
    const float* Wd = W_down + (size_t)c * FCH * DD;
    gemm_k<EPI_GU><<<dim3(FCH / 64, MM / 64), 256, 0, stream>>>(
        s3, Wg, Wu, s0, nullptr, nullptr, nullptr, nullptr,
        MM, FCH, DD, DD, FF, FCH);
    gemm_k<EPI_ADD><<<dim3(DD / 64, MM / 64), 256, 0, stream>>>(
        s0, Wd, nullptr, out, nullptr, (c == 0 ? s2 : out), nullptr, nullptr,
        MM, DD, FCH, FCH, DD, DD);
  }
}

// Round 3
// 2488.518 us; speedup vs baseline: 2.7498x; 2.7498x over previous
//
#include <hip/hip_runtime.h>
#include <hip/hip_bf16.h>
#include <math.h>

// Problem constants (B=2, S=2048, D=2048, H=16, HD=128, F=8192)
#define BB 2
#define SS 2048
#define DD 2048
#define HH 16
#define HD 128
#define FF 8192
#define MM (BB*SS)          // 4096 rows
#define CL 64               // scan chunk length
#define NC (SS/CL)          // 32 chunks
#define FCH 2048            // MLP F-chunk width (4 chunks)

#define DEVI __device__ __forceinline__
typedef unsigned short u16;
typedef __attribute__((ext_vector_type(8))) short bf16x8;
typedef __attribute__((ext_vector_type(4))) float f32x4;

DEVI float gelu_f(float x) {
  float x3 = x * x * x;
  return 0.5f * x * (1.0f + tanhf(0.7978845608028654f * (x + 0.044715f * x3)));
}
DEVI float sigmoid_f(float x) { return 1.0f / (1.0f + expf(-x)); }

DEVI u16 f2b(float v) {                 // f32 -> bf16 RNE
  union { float f; unsigned u; } x; x.f = v;
  unsigned r = x.u + 0x7fffu + ((x.u >> 16) & 1u);
  return (u16)(r >> 16);
}
DEVI float b2f(u16 b) {
  union { unsigned u; float f; } x; x.u = ((unsigned)b) << 16;
  return x.f;
}

DEVI void gload16(const u16* g, u16* l) {   // 16B global -> LDS (wave-uniform dest)
  __builtin_amdgcn_global_load_lds((const __attribute__((address_space(1))) void*)g,
                                   (__attribute__((address_space(3))) void*)l, 16, 0, 0);
}

// ---------------- RMSNorm -> split bf16 hi/lo ----------------
__global__ __launch_bounds__(256) void rmsnorm_split_k(const float* __restrict__ x,
                                                       const float* __restrict__ w,
                                                       u16* __restrict__ oh,
                                                       u16* __restrict__ ol) {
  size_t row = blockIdx.x;
  const float* xr = x + row * DD;
  int tid = threadIdx.x;
  float ss = 0.f;
#pragma unroll
  for (int i = 0; i < 2; ++i) {
    float4 v = *(const float4*)&xr[tid * 4 + i * 1024];
    ss += v.x * v.x + v.y * v.y + v.z * v.z + v.w * v.w;
  }
#pragma unroll
  for (int off = 32; off > 0; off >>= 1) ss += __shfl_down(ss, off, 64);
  __shared__ float sred[4];
  if ((tid & 63) == 0) sred[tid >> 6] = ss;
  __syncthreads();
  float scale = rsqrtf((sred[0] + sred[1] + sred[2] + sred[3]) * (1.0f / DD) + 1e-6f);
#pragma unroll
  for (int i = 0; i < 2; ++i) {
    int idx = tid * 4 + i * 1024;
    float4 v = *(const float4*)&xr[idx];
    float4 wv = *(const float4*)&w[idx];
    float vv[4] = {v.x * scale * wv.x, v.y * scale * wv.y,
                   v.z * scale * wv.z, v.w * scale * wv.w};
#pragma unroll
    for (int j = 0; j < 4; ++j) {
      u16 h = f2b(vv[j]);
      oh[row * DD + idx + j] = h;
      ol[row * DD + idx + j] = f2b(vv[j] - b2f(h));
    }
  }
}

// ---------------- causal depthwise conv1d, K=4 ----------------
__global__ __launch_bounds__(256) void conv_k(const float* __restrict__ xb,
                                              const float* __restrict__ cw,
                                              const float* __restrict__ cb,
                                              float* __restrict__ xc) {
  int idx = blockIdx.x * 256 + threadIdx.x;
  const int D4 = DD / 4;
  if (idx >= BB * SS * D4) return;
  int d4 = idx % D4;
  int bs = idx / D4;
  int s = bs % SS;
  int d = d4 * 4;
  float4 acc = *(const float4*)&cb[d];
  const float* base = xb + (size_t)(bs - s) * DD + d;
#pragma unroll
  for (int k = 0; k < 4; ++k) {
    int sp = s + k - 3;
    if (sp >= 0) {
      float4 w = *(const float4*)&cw[k * DD + d];
      float4 v = *(const float4*)&base[(size_t)sp * DD];
      acc.x = fmaf(w.x, v.x, acc.x); acc.y = fmaf(w.y, v.y, acc.y);
      acc.z = fmaf(w.z, v.z, acc.z); acc.w = fmaf(w.w, v.w, acc.w);
    }
  }
  *(float4*)&xc[(size_t)bs * DD + d] = acc;
}

// ---------------- chunked scan (3 passes) ----------------
__global__ __launch_bounds__(256) void scan1_k(const float* __restrict__ a,
                                               const float* __restrict__ bx,
                                               float* __restrict__ cA,
                                               float* __restrict__ cB) {
  int idx = blockIdx.x * 256 + threadIdx.x;
  if (idx >= BB * NC * DD) return;
  int d = idx % DD;
  int t = idx / DD;
  int c = t % NC;
  int b = t / NC;
  size_t base = ((size_t)b * SS + (size_t)c * CL) * DD + d;
  float A = 1.f, Bv = 0.f;
  for (int s = 0; s < CL; ++s) {
    float av = a[base + (size_t)s * DD];
    float bv = bx[base + (size_t)s * DD];
    A = av * A;
    Bv = fmaf(av, Bv, bv);
  }
  size_t o = ((size_t)b * NC + c) * DD + d;
  cA[o] = A;
  cB[o] = Bv;
}

__global__ __launch_bounds__(256) void scan2_k(const float* __restrict__ cA,
                                               const float* __restrict__ cB,
                                               const float* __restrict__ h0,
                                               float* __restrict__ carry,
                                               float* __restrict__ hlast) {
  int idx = blockIdx.x * 256 + threadIdx.x;
  if (idx >= BB * DD) return;
  int d = idx % DD;
  int b = idx / DD;
  float h = h0[(size_t)b * DD + d];
  for (int c = 0; c < NC; ++c) {
    size_t o = ((size_t)b * NC + c) * DD + d;
    carry[o] = h;
    h = fmaf(cA[o], h, cB[o]);
  }
  hlast[(size_t)b * DD + d] = h;
}

__global__ __launch_bounds__(256) void scan3_k(const float* __restrict__ a,
                                               const float* __restrict__ bx,
                                               const float* __restrict__ carry,
                                               float* __restrict__ lru) {
  int idx = blockIdx.x * 256 + threadIdx.x;
  if (idx >= BB * NC * DD) return;
  int d = idx % DD;
  int t = idx / DD;
  int c = t % NC;
  int b = t / NC;
  size_t base = ((size_t)b * SS + (size_t)c * CL) * DD + d;
  float h = carry[((size_t)b * NC + c) * DD + d];
  for (int s = 0; s < CL; ++s) {
    float av = a[base + (size_t)s * DD];
    float bv = bx[base + (size_t)s * DD];
    h = fmaf(av, h, bv);
    lru[base + (size_t)s * DD] = h;
  }
}

// ---------------- yl = y * lru -> split bf16 ----------------
__global__ __launch_bounds__(256) void mul_split_k(const float* __restrict__ y,
                                                   const float* __restrict__ lru,
                                                   u16* __restrict__ oh,
                                                   u16* __restrict__ ol) {
  int i = blockIdx.x * 256 + threadIdx.x;
  if (i >= (MM * DD) / 4) return;
  float4 a = ((const float4*)y)[i];
  float4 b = ((const float4*)lru)[i];
  float v[4] = {a.x * b.x, a.y * b.y, a.z * b.z, a.w * b.w};
#pragma unroll
  for (int j = 0; j < 4; ++j) {
    u16 h = f2b(v[j]);
    oh[i * 4 + j] = h;
    ol[i * 4 + j] = f2b(v[j] - b2f(h));
  }
}

// ---------------- transpose + split weights: W[K][N] f32 -> T[N][K] bf16 hi/lo ----------------
__global__ __launch_bounds__(256) void tsplit_k(const float* __restrict__ Wsrc,
                                                u16* __restrict__ Th, u16* __restrict__ Tl,
                                                int K, int ld) {
  __shared__ float t[32][33];
  int k0 = blockIdx.y * 32, n0 = blockIdx.x * 32;
  int c = threadIdx.x & 31, r4 = threadIdx.x >> 5;
#pragma unroll
  for (int i = 0; i < 4; ++i) {
    int r = r4 * 4 + i;
    t[r][c] = Wsrc[(size_t)(k0 + r) * ld + n0 + c];
  }
  __syncthreads();
#pragma unroll
  for (int i = 0; i < 4; ++i) {
    int r = r4 * 4 + i;
    float v = t[c][r];                      // = W[k0+c][n0+r]
    u16 h = f2b(v);
    size_t o = (size_t)(n0 + r) * K + k0 + c;
    Th[o] = h;
    Tl[o] = f2b(v - b2f(h));
  }
}

// ---------------- old VALU gemm, kept only for the tiny per-head gates ----------------
__global__ __launch_bounds__(256) void gates_k(
    const float* __restrict__ A, const float* __restrict__ B0,
    const float* __restrict__ B1, float* __restrict__ O0,
    float* __restrict__ O1, const float* __restrict__ aux0,
    const float* __restrict__ aux1, const float* __restrict__ aux2) {
  constexpr int BK = 16;
  __shared__ float As[BK][64 + 4];
  __shared__ float Bs0[BK][64];
  __shared__ float Bs1[BK][64];
  int h = blockIdx.z;
  A += h * HD; B0 += h * HD * HD; B1 += h * HD * HD;
  O0 += h * HD; O1 += h * HD;
  aux0 += h * HD; aux1 += h * HD; aux2 += h * HD;

  int tid = threadIdx.x;
  int tx = tid & 15, ty = tid >> 4;
  int m0 = blockIdx.y * 64, n0 = blockIdx.x * 64;
  int ar = tid >> 2, ac = (tid & 3) << 2;
  int br = tid >> 4, bc = (tid & 15) << 2;

  const float* Aptr = A + (size_t)(m0 + ar) * DD + ac;
  const float* B0ptr = B0 + (size_t)br * HD + n0 + bc;
  const float* B1ptr = B1 + (size_t)br * HD + n0 + bc;

  float acc0[4][4] = {};
  float acc1[4][4] = {};
  for (int kk = 0; kk < HD; kk += BK) {
    float4 av = *(const float4*)(Aptr + kk);
    float4 b0 = *(const float4*)(B0ptr + (size_t)kk * HD);
    float4 b1 = *(const float4*)(B1ptr + (size_t)kk * HD);
    As[ac + 0][ar] = av.x; As[ac + 1][ar] = av.y;
    As[ac + 2][ar] = av.z; As[ac + 3][ar] = av.w;
    *(float4*)&Bs0[br][bc] = b0;
    *(float4*)&Bs1[br][bc] = b1;
    __syncthreads();
#pragma unroll
    for (int k = 0; k < BK; ++k) {
      float4 a4 = *(const float4*)&As[k][ty << 2];
      float4 p4 = *(const float4*)&Bs0[k][tx << 2];
      float4 q4 = *(const float4*)&Bs1[k][tx << 2];
      float avr[4] = {a4.x, a4.y, a4.z, a4.w};
      float b0v[4] = {p4.x, p4.y, p4.z, p4.w};
      float b1v[4] = {q4.x, q4.y, q4.z, q4.w};
#pragma unroll
      for (int i = 0; i < 4; ++i)
#pragma unroll
        for (int j = 0; j < 4; ++j) {
          acc0[i][j] = fmaf(avr[i], b0v[j], acc0[i][j]);
          acc1[i][j] = fmaf(avr[i], b1v[j], acc1[i][j]);
        }
    }
    __syncthreads();
  }
  int grow = m0 + (ty << 2);
  int gcol = n0 + (tx << 2);
#pragma unroll
  for (int i = 0; i < 4; ++i) {
    size_t ro = (size_t)(grow + i) * DD + gcol;
#pragma unroll
    for (int j = 0; j < 4; ++j) {
      float rv = sigmoid_f(acc0[i][j] + aux0[gcol + j]);   // agate
      float iv = sigmoid_f(acc1[i][j] + aux1[gcol + j]);   // igate
      float ap = aux2[gcol + j];
      float sp = log1pf(expf(-ap));
      float la = -8.0f * rv * sp;
      float mult = sqrtf(fmaxf(1.0f - expf(2.0f * la), 0.0f));
      float xrv = A[(size_t)(grow + i) * DD + gcol + j];
      O0[ro + j] = expf(la);
      O1[ro + j] = mult * iv * xrv;
    }
  }
}

// ---------------- MFMA split-bf16 GEMM: C = A @ B (+ dual B1) ----------------
// A: [M][K] as hi/lo bf16 (lda=K). B given transposed: BT[N][K] hi/lo (ldb=K).
// 128x128 tile, 4 waves (2x2 of 64x64), BK=32, mfma_f32_16x16x32_bf16,
// 3-term split product per fragment pair.
enum { MG_YX = 0, MG_GU = 1, MG_ADD = 2 };

template <int EPI, bool DUAL>
__global__ __launch_bounds__(256) void mgemm_k(
    const u16* __restrict__ Ah, const u16* __restrict__ Al,
    const u16* __restrict__ B0h, const u16* __restrict__ B0l,
    const u16* __restrict__ B1h, const u16* __restrict__ B1l,
    void* __restrict__ O0, void* __restrict__ O1,
    const float* __restrict__ aux,
    int M, int N, int K) {
  __shared__ u16 lds[(DUAL ? 6 : 4) * 4096];   // buffers of 128x32 bf16 (8KB each)

  int tid = threadIdx.x;
  int w = tid >> 6, l = tid & 63;
  int m0 = blockIdx.y * 128, n0 = blockIdx.x * 128;
  int wr = w >> 1, wc = w & 1;

  // staging geometry: each wave stages 2 x 16-row groups per buffer
  int srow = l >> 2;
  int sk = (l & 3) * 8;
  int g0 = (w * 2) * 16 + srow;
  int g1 = (w * 2 + 1) * 16 + srow;
  int d0 = (w * 2) * 512;        // LDS element offset of 16-row group (1KB=512 u16)
  int d1 = (w * 2 + 1) * 512;

  const u16* gAh0 = Ah + (size_t)(m0 + g0) * K + sk;
  const u16* gAh1 = Ah + (size_t)(m0 + g1) * K + sk;
  const u16* gAl0 = Al + (size_t)(m0 + g0) * K + sk;
  const u16* gAl1 = Al + (size_t)(m0 + g1) * K + sk;
  const u16* gB0h0 = B0h + (size_t)(n0 + g0) * K + sk;
  const u16* gB0h1 = B0h + (size_t)(n0 + g1) * K + sk;
  const u16* gB0l0 = B0l + (size_t)(n0 + g0) * K + sk;
  const u16* gB0l1 = B0l + (size_t)(n0 + g1) * K + sk;
  const u16* gB1h0 = DUAL ? B1h + (size_t)(n0 + g0) * K + sk : nullptr;
  const u16* gB1h1 = DUAL ? B1h + (size_t)(n0 + g1) * K + sk : nullptr;
  const u16* gB1l0 = DUAL ? B1l + (size_t)(n0 + g0) * K + sk : nullptr;
  const u16* gB1l1 = DUAL ? B1l + (size_t)(n0 + g1) * K + sk : nullptr;

  f32x4 acc0[4][4] = {};
  f32x4 acc1[4][4] = {};

  int fr = l & 15;          // fragment row/col within 16
  int fs = (l >> 4) * 8;    // k-slot

  for (int kk = 0; kk < K; kk += 32) {
    gload16(gAh0 + kk, lds + 0 * 4096 + d0);
    gload16(gAh1 + kk, lds + 0 * 4096 + d1);
    gload16(gAl0 + kk, lds + 1 * 4096 + d0);
    gload16(gAl1 + kk, lds + 1 * 4096 + d1);
    gload16(gB0h0 + kk, lds + 2 * 4096 + d0);
    gload16(gB0h1 + kk, lds + 2 * 4096 + d1);
    gload16(gB0l0 + kk, lds + 3 * 4096 + d0);
    gload16(gB0l1 + kk, lds + 3 * 4096 + d1);
    if constexpr (DUAL) {
      gload16(gB1h0 + kk, lds + 4 * 4096 + d0);
      gload16(gB1h1 + kk, lds + 4 * 4096 + d1);
      gload16(gB1l0 + kk, lds + 5 * 4096 + d0);
      gload16(gB1l1 + kk, lds + 5 * 4096 + d1);
    }
    __syncthreads();

    bf16x8 ah[4], al[4];
#pragma unroll
    for (int mi = 0; mi < 4; ++mi) {
      int r = wr * 64 + mi * 16 + fr;
      ah[mi] = *(const bf16x8*)&lds[0 * 4096 + r * 32 + fs];
      al[mi] = *(const bf16x8*)&lds[1 * 4096 + r * 32 + fs];
    }
#pragma unroll
    for (int ni = 0; ni < 4; ++ni) {
      int c = wc * 64 + ni * 16 + fr;
      bf16x8 b0h = *(const bf16x8*)&lds[2 * 4096 + c * 32 + fs];
      bf16x8 b0l = *(const bf16x8*)&lds[3 * 4096 + c * 32 + fs];
#pragma unroll
      for (int mi = 0; mi < 4; ++mi) {
        acc0[mi][ni] = __builtin_amdgcn_mfma_f32_16x16x32_bf16(ah[mi], b0h, acc0[mi][ni], 0, 0, 0);
        acc0[mi][ni] = __builtin_amdgcn_mfma_f32_16x16x32_bf16(ah[mi], b0l, acc0[mi][ni], 0, 0, 0);
        acc0[mi][ni] = __builtin_amdgcn_mfma_f32_16x16x32_bf16(al[mi], b0h, acc0[mi][ni], 0, 0, 0);
      }
      if constexpr (DUAL) {
        bf16x8 b1h = *(const bf16x8*)&lds[4 * 4096 + c * 32 + fs];
        bf16x8 b1l = *(const bf16x8*)&lds[5 * 4096 + c * 32 + fs];
#pragma unroll
        for (int mi = 0; mi < 4; ++mi) {
          acc1[mi][ni] = __builtin_amdgcn_mfma_f32_16x16x32_bf16(ah[mi], b1h, acc1[mi][ni], 0, 0, 0);
          acc1[mi][ni] = __builtin_amdgcn_mfma_f32_16x16x32_bf16(ah[mi], b1l, acc1[mi][ni], 0, 0, 0);
          acc1[mi][ni] = __builtin_amdgcn_mfma_f32_16x16x32_bf16(al[mi], b1h, acc1[mi][ni], 0, 0, 0);
        }
      }
    }
    __syncthreads();
  }

  // epilogue: C/D layout col=lane&15, row=(lane>>4)*4+reg
  int fq = l >> 4;
#pragma unroll
  for (int mi = 0; mi < 4; ++mi) {
#pragma unroll
    for (int ni = 0; ni < 4; ++ni) {
#pragma unroll
      for (int r = 0; r < 4; ++r) {
        int row = m0 + wr * 64 + mi * 16 + fq * 4 + r;
        int col = n0 + wc * 64 + ni * 16 + fr;
        size_t o = (size_t)row * N + col;
        float v = acc0[mi][ni][r];
        if constexpr (EPI == MG_YX) {
          ((float*)O0)[o] = gelu_f(v);
          ((float*)O1)[o] = acc1[mi][ni][r];
        } else if constexpr (EPI == MG_GU) {
          float t = gelu_f(v) * acc1[mi][ni][r];
          u16 h = f2b(t);
          ((u16*)O0)[o] = h;
          ((u16*)O1)[o] = f2b(t - b2f(h));
        } else {  // MG_ADD
          ((float*)O0)[o] = v + aux[o];
        }
      }
    }
  }
}

extern "C" void kernel_launch(void* const* d_in, const int* in_sizes, int n_in,
                              void* d_out, int out_size, void* d_ws, size_t ws_size,
                              hipStream_t stream) {
  const float* x       = (const float*)d_in[0];
  const float* hidden  = (const float*)d_in[1];
  const float* rms1_w  = (const float*)d_in[2];
  const float* rms2_w  = (const float*)d_in[3];
  const float* W_x     = (const float*)d_in[4];
  const float* W_y     = (const float*)d_in[5];
  const float* conv_w  = (const float*)d_in[6];
  const float* conv_b  = (const float*)d_in[7];
  const float* a_param = (const float*)d_in[8];
  const float* igate_w = (const float*)d_in[9];
  const float* igate_b = (const float*)d_in[10];
  const float* agate_w = (const float*)d_in[11];
  const float* agate_b = (const float*)d_in[12];
  const float* W_out   = (const float*)d_in[13];
  const float* W_gate  = (const float*)d_in[14];
  const float* W_up    = (const float*)d_in[15];
  const float* W_down  = (const float*)d_in[16];

  float* out   = (float*)d_out;
  float* hlast = out + (size_t)MM * DD;

  // 4 x 32MB slots + 1.57MB scan = 135.79MB (same footprint that passed in R2)
  const size_t E = (size_t)MM * DD;       // 8388608 elements
  const size_t WD = (size_t)DD * DD;      // 4194304 elements (also D*FCH, FCH*D)
  const size_t SLOT = 33554432;           // bytes
  char* wsb = (char*)d_ws;
  char* SA = wsb;
  char* SB = wsb + SLOT;
  char* SC = wsb + 2 * SLOT;
  char* SD = wsb + 3 * SLOT;
  float* cA    = (float*)(wsb + 4 * SLOT);
  float* cB    = cA + (size_t)BB * NC * DD;
  float* carry = cB + (size_t)BB * NC * DD;

  // SA phases: nh/nl -> bx -> residual
  u16* nh = (u16*)SA;           u16* nl = nh + E;
  float* bx = (float*)SA;
  float* residual = (float*)SA;
  // SB phases: y -> WoT -> n2
  float* y = (float*)SB;
  u16* WoTh = (u16*)SB;         u16* WoTl = WoTh + WD;
  u16* n2h = (u16*)SB;          u16* n2l = n2h + E;
  // SC phases: xb -> a -> ylh/yll -> th/tl
  float* xb = (float*)SC;
  float* a_arr = (float*)SC;
  u16* ylh = (u16*)SC;          u16* yll = ylh + E;
  u16* th = (u16*)SC;           u16* tl = th + E;
  // SD phases: WyT/WxT -> xc -> lru -> WgT/WuT -> WdT
  u16* WyTh = (u16*)SD;         u16* WyTl = WyTh + WD;
  u16* WxTh = WyTl + WD;        u16* WxTl = WxTh + WD;
  float* xc = (float*)SD;
  float* lru = (float*)SD;
  u16* WgTh = (u16*)SD;         u16* WgTl = WgTh + WD;
  u16* WuTh = WgTl + WD;        u16* WuTl = WuTh + WD;
  u16* WdTh = (u16*)SD;         u16* WdTl = WdTh + WD;

  const dim3 g128(DD / 128, MM / 128);    // (16, 32)
  const dim3 gT(DD / 32, DD / 32);

  // 1. normed = rmsnorm(x) -> split (SA)
  rmsnorm_split_k<<<MM, 256, 0, stream>>>(x, rms1_w, nh, nl);

  // 1b. transpose+split W_y, W_x (SD)
  tsplit_k<<<gT, 256, 0, stream>>>(W_y, WyTh, WyTl, DD, DD);
  tsplit_k<<<gT, 256, 0, stream>>>(W_x, WxTh, WxTl, DD, DD);

  // 2. y = gelu(normed@W_y) -> SB ; xb = normed@W_x -> SC
  mgemm_k<MG_YX, true><<<g128, 256, 0, stream>>>(
      nh, nl, WyTh, WyTl, WxTh, WxTl, y, xb, nullptr, MM, DD, DD);

  // 3. xc = conv(xb) -> SD (weights dead)
  conv_k<<<(BB * SS * (DD / 4) + 255) / 256, 256, 0, stream>>>(xb, conv_w, conv_b, xc);

  // 4. gates: a -> SC (xb dead), bx -> SA (normed dead)
  gates_k<<<dim3(HD / 64, MM / 64, HH), 256, 0, stream>>>(
      xc, agate_w, igate_w, a_arr, bx, agate_b, igate_b, a_param);

  // 5-7. chunked scan -> lru (SD, xc dead), h_last
  scan1_k<<<(BB * NC * DD + 255) / 256, 256, 0, stream>>>(a_arr, bx, cA, cB);
  scan2_k<<<(BB * DD + 255) / 256, 256, 0, stream>>>(cA, cB, hidden, carry, hlast);
  scan3_k<<<(BB * NC * DD + 255) / 256, 256, 0, stream>>>(a_arr, bx, carry, lru);

  // 8. yl = y * lru -> split (SC, a dead)
  mul_split_k<<<(MM * DD / 4 + 255) / 256, 256, 0, stream>>>(y, lru, ylh, yll);

  // 8b. transpose+split W_out -> SB front (y dead)
  tsplit_k<<<gT, 256, 0, stream>>>(W_out, WoTh, WoTl, DD, DD);

  // 9. residual = yl@W_out + x -> SA (bx dead)
  mgemm_k<MG_ADD, false><<<g128, 256, 0, stream>>>(
      ylh, yll, WoTh, WoTl, nullptr, nullptr, residual, nullptr, x, MM, DD, DD);

  // 10. n2 = rmsnorm(residual) -> split (SB, WoT dead)
  rmsnorm_split_k<<<MM, 256, 0, stream>>>(residual, rms2_w, n2h, n2l);

  // 11+12. gated MLP chunked over F (4 chunks of 2048)
  for (int c = 0; c < FF / FCH; ++c) {
    tsplit_k<<<dim3(FCH / 32, DD / 32), 256, 0, stream>>>(
        W_gate + (size_t)c * FCH, WgTh, WgTl, DD, FF);
    tsplit_k<<<dim3(FCH / 32, DD / 32), 256, 0, stream>>>(
        W_up + (size_t)c * FCH, WuTh, WuTl, DD, FF);
    mgemm_k<MG_GU, true><<<dim3(FCH / 128, MM / 128), 256, 0, stream>>>(
        n2h, n2l, WgTh, WgTl, WuTh, WuTl, th, tl, nullptr, MM, FCH, DD);
    tsplit_k<<<dim3(DD / 32, FCH / 32), 256, 0, stream>>>(
        W_down + (size_t)c * FCH * DD, WdTh, WdTl, FCH, DD);
    mgemm_k<MG_ADD, false><<<g128, 256, 0, stream>>>(
        th, tl, WdTh, WdTl, nullptr, nullptr, out, nullptr,
        (c == 0 ? residual : out), MM, DD, FCH);
  }
}